// Round 1
// baseline (439.077 us; speedup 1.0000x reference)
//
#include <hip/hip_runtime.h>
#include <hip/hip_bf16.h>
#include <cmath>

// Problem constants
#define TT 3
#define HH 64
#define WW 64
#define NPIX 4096       // 64*64
#define NHEADS 4
#define CHD 64
#define DIMD 256
#define PS 7
#define WS 9
#define WSH 4
#define KS 16
#define KA 8
#define NG 32           // grid points per dim (stride 2)
#define QTOT 3072       // T*32*32
#define NOFF 81
#define SCALE 0.125f

// Workspace offsets (floats)
#define OFF_DW   ((size_t)0)                 // [3type][3t][256][4096] = 9,437,184
#define OFF_Q    ((size_t)9437184)           // [t][ch][pix] 3,145,728
#define OFF_K    ((size_t)12582912)          // [t][ch][pix]
#define OFF_V    ((size_t)15728640)          // [t][pix][ch]
#define OFF_D    ((size_t)18874368)          // [81][12][4096] = 3,981,312
#define OFF_DG   ((size_t)22855680)          // [12288][81] = 995,328
#define OFF_ATTN ((size_t)23851008)          // [12288][8]
#define OFF_INDS ((size_t)23949312)          // [12288][8] int
#define OFF_VACC ((size_t)24047616)          // [t][pix][256] 3,145,728
#define OFF_ZV   ((size_t)27193344)          // [12288]
// total 27,205,632 floats = 108.8 MB

__device__ __forceinline__ int reflect_i(int i, int n) {
  i = i < 0 ? -i : i;
  return i >= n ? 2 * (n - 1) - i : i;
}

// K1: depthwise 3x3, zero padding, for q/k/v in one pass.
__global__ void k_dw(const float* __restrict__ vid,
                     const float* __restrict__ qdw, const float* __restrict__ kdw,
                     const float* __restrict__ vdw, float* __restrict__ dw) {
  int plane = blockIdx.x;          // t*256+ch
  int ch = plane & 255;
  const float* src = vid + (size_t)plane * NPIX;
  float wq[9], wk[9], wv[9];
#pragma unroll
  for (int i = 0; i < 9; i++) { wq[i] = qdw[ch*9+i]; wk[i] = kdw[ch*9+i]; wv[i] = vdw[ch*9+i]; }
  int x = threadIdx.x, ty = threadIdx.y;   // (64,4)
  for (int yb = 0; yb < 16; ++yb) {
    int y = yb * 4 + ty;
    float aq = 0, ak = 0, av = 0;
#pragma unroll
    for (int a = 0; a < 3; a++) {
      int yy = y + a - 1;
      if (yy < 0 || yy >= HH) continue;
#pragma unroll
      for (int b = 0; b < 3; b++) {
        int xx = x + b - 1;
        if (xx < 0 || xx >= WW) continue;
        float xv = src[yy * WW + xx];
        aq += xv * wq[a*3+b]; ak += xv * wk[a*3+b]; av += xv * wv[a*3+b];
      }
    }
    size_t o = (size_t)plane * NPIX + y * WW + x;
    dw[o] = aq;
    dw[(size_t)3145728 + o] = ak;
    dw[(size_t)6291456 + o] = av;
  }
}

// K2: pointwise GEMM. OUT[o,pix] = sum_c W[o,c]*DW[c,pix] (+bias; q scaled).
// grid (64 pixtiles, 4 otiles, 9=type*3+t), block 256
__global__ void k_pw(const float* __restrict__ dw,
                     const float* __restrict__ qpw, const float* __restrict__ qb,
                     const float* __restrict__ kpw, const float* __restrict__ kb,
                     const float* __restrict__ vpw, const float* __restrict__ vb,
                     float* __restrict__ qo, float* __restrict__ ko, float* __restrict__ vo) {
  int type = blockIdx.z / 3, t = blockIdx.z % 3;
  const float* W   = type == 0 ? qpw : (type == 1 ? kpw : vpw);
  const float* bia = type == 0 ? qb  : (type == 1 ? kb  : vb);
  const float* A = dw + (size_t)type * 3145728 + (size_t)t * 1048576;  // [256][4096]
  int p0 = blockIdx.x * 64, o0 = blockIdx.y * 64;
  __shared__ float sW[16][65], sA[16][65];
  int tid = threadIdx.x;
  int ty = tid >> 4, tx = tid & 15;
  float acc[4][4] = {};
  for (int k0 = 0; k0 < 256; k0 += 16) {
    {
      int i = tid >> 4, j = tid & 15;
#pragma unroll
      for (int r = 0; r < 4; r++) sW[j][i + 16*r] = W[(size_t)(o0 + i + 16*r) * 256 + k0 + j];
    }
    {
      int c = tid >> 6, px = tid & 63;
#pragma unroll
      for (int r = 0; r < 4; r++) sA[c + 4*r][px] = A[(size_t)(k0 + c + 4*r) * NPIX + p0 + px];
    }
    __syncthreads();
#pragma unroll
    for (int kk = 0; kk < 16; kk++) {
      float a[4], b[4];
#pragma unroll
      for (int i = 0; i < 4; i++) a[i] = sW[kk][ty*4+i];
#pragma unroll
      for (int j = 0; j < 4; j++) b[j] = sA[kk][tx*4+j];
#pragma unroll
      for (int i = 0; i < 4; i++)
#pragma unroll
        for (int j = 0; j < 4; j++) acc[i][j] += a[i] * b[j];
    }
    __syncthreads();
  }
#pragma unroll
  for (int i = 0; i < 4; i++) {
    int o = o0 + ty*4 + i;
    float bb = bia[o];
#pragma unroll
    for (int j = 0; j < 4; j++) {
      int p = p0 + tx*4 + j;
      float vvv = acc[i][j] + bb;
      if (type == 0)      qo[((size_t)t*256 + o) * NPIX + p] = vvv * SCALE;
      else if (type == 1) ko[((size_t)t*256 + o) * NPIX + p] = vvv;
      else                vo[((size_t)(t*NPIX + p)) * 256 + o] = vvv;
    }
  }
}

// K3a: per-pixel dot maps D[n][t*4+h][y][x] = sum_c q[c,y,x]*k[c,refl(y+dy),refl(x+dx)]
// grid 768 = (t*4+h)*64+y, block 256 (4 groups of 64 lanes split dx)
__global__ void k_dist(const float* __restrict__ q, const float* __restrict__ k,
                       float* __restrict__ D) {
  int b = blockIdx.x;
  int y = b & 63, th = b >> 6;
  int t = th >> 2, h = th & 3;
  __shared__ float sQ[64][64];   // [c][x]
  __shared__ float sK[64][64];
  int tid = threadIdx.x;
  int x = tid & 63, w = tid >> 6;
  const float* qp = q + ((size_t)t * 256 + h * 64) * NPIX;
  const float* kp = k + ((size_t)t * 256 + h * 64) * NPIX;
  for (int i = tid; i < 4096; i += 256)
    sQ[i >> 6][i & 63] = qp[(size_t)(i >> 6) * NPIX + y * WW + (i & 63)];
  for (int dyi = 0; dyi < 9; ++dyi) {
    int yk = reflect_i(y + dyi - 4, HH);
    __syncthreads();
    for (int i = tid; i < 4096; i += 256)
      sK[i >> 6][i & 63] = kp[(size_t)(i >> 6) * NPIX + yk * WW + (i & 63)];
    __syncthreads();
    for (int dxi = w; dxi < 9; dxi += 4) {
      int xk = reflect_i(x + dxi - 4, WW);
      float s = 0.f;
#pragma unroll 16
      for (int c = 0; c < 64; c++) s += sQ[c][x] * sK[c][xk];
      D[((size_t)(dyi * 9 + dxi) * 12 + th) * NPIX + y * WW + x] = s;
    }
  }
}

// K3b: 7x7 reflected box sum at grid points. grid (12, 81), block 256
__global__ void k_box(const float* __restrict__ D, float* __restrict__ DG) {
  int th = blockIdx.x, n = blockIdx.y;
  int t = th >> 2, h = th & 3;
  __shared__ float sD[4096];
  int tid = threadIdx.x;
  const float* Dp = D + ((size_t)n * 12 + th) * NPIX;
  for (int i = tid; i < 4096; i += 256) sD[i] = Dp[i];
  __syncthreads();
  for (int qi = tid; qi < 1024; qi += 256) {
    int gy = qi >> 5, gx = qi & 31;
    int yq = gy * 2, xq = gx * 2;
    float s = 0.f;
#pragma unroll
    for (int py = 0; py < 7; py++) {
      int ry = yq + py; ry = ry >= HH ? 126 - ry : ry;
      const float* row = sD + ry * WW;
#pragma unroll
      for (int px = 0; px < 7; px++) {
        int rx = xq + px; rx = rx >= WW ? 126 - rx : rx;
        s += row[rx];
      }
    }
    DG[((size_t)h * QTOT + t * 1024 + qi) * NOFF + n] = s;
  }
}

// K3c: top-16 selection (stable, lowest index wins ties), softmax over 16, keep 8.
__global__ void k_topk(const float* __restrict__ DG, float* __restrict__ attn,
                       int* __restrict__ inds) {
  int r = blockIdx.x * 256 + threadIdx.x;
  if (r >= NHEADS * QTOT) return;
  const float* row = DG + (size_t)r * NOFF;
  float dv[NOFF];
#pragma unroll
  for (int i = 0; i < NOFF; i++) dv[i] = row[i];
  float vals[KS]; int idx[KS];
#pragma unroll
  for (int s = 0; s < KS; s++) {
    float best = -1e30f; int bi = 0;
#pragma unroll
    for (int i = 0; i < NOFF; i++) {
      if (dv[i] > best) { best = dv[i]; bi = i; }
    }
    vals[s] = best; idx[s] = bi;
#pragma unroll
    for (int i = 0; i < NOFF; i++) dv[i] = (i == bi) ? -1e30f : dv[i];
  }
  float m = vals[0], den = 0.f, e[KS];
#pragma unroll
  for (int s = 0; s < KS; s++) { e[s] = expf(vals[s] - m); den += e[s]; }
  float inv = 1.f / den;
#pragma unroll
  for (int s = 0; s < KA; s++) {
    attn[(size_t)r * KA + s] = e[s] * inv;
    inds[(size_t)r * KA + s] = idx[s];
  }
}

// zv counts
__global__ void k_zv(float* __restrict__ zv) {
  int q = blockIdx.x * 256 + threadIdx.x;
  if (q >= QTOT) return;
  int t = q >> 10, rem = q & 1023, gy = rem >> 5, gx = rem & 31;
  int yq = gy * 2, xq = gx * 2;
#pragma unroll
  for (int py = 0; py < 7; py++) {
    int ry = yq + py; ry = ry >= HH ? 126 - ry : ry;
#pragma unroll
    for (int px = 0; px < 7; px++) {
      int rx = xq + px; rx = rx >= WW ? 126 - rx : rx;
      atomicAdd(zv + t * NPIX + ry * WW + rx, 1.0f);
    }
  }
}

// K4: aggregation + scatter (pre-projection channel space).
// grid (3072, 4) = (query, head), block 256
__global__ void k_agg(const float* __restrict__ v, const float* __restrict__ attn,
                      const int* __restrict__ inds, float* __restrict__ vacc) {
  int q = blockIdx.x, h = blockIdx.y;
  int t = q >> 10, rem = q & 1023, gy = rem >> 5, gx = rem & 31;
  int yq = gy * 2, xq = gx * 2;
  int r = h * QTOT + q;
  __shared__ float w[8];
  __shared__ int dys[8], dxs[8];
  if (threadIdx.x < 8) {
    w[threadIdx.x] = attn[(size_t)r * KA + threadIdx.x];
    int id = inds[(size_t)r * KA + threadIdx.x];
    dys[threadIdx.x] = id / 9 - 4;
    dxs[threadIdx.x] = id % 9 - 4;
  }
  __syncthreads();
  int tid = threadIdx.x;
  int c = tid & 63;
  const float* vp = v + (size_t)t * NPIX * 256 + h * 64 + c;
  float* op = vacc + (size_t)t * NPIX * 256 + h * 64 + c;
  for (int item = tid; item < 49 * 64; item += 256) {
    int p = item >> 6;
    int py = p / 7, px = p - py * 7;
    float acc = 0.f;
#pragma unroll
    for (int n = 0; n < 8; n++) {
      int ry = yq + dys[n] + py; ry = ry < 0 ? -ry : ry; ry = ry >= HH ? 126 - ry : ry;
      int rx = xq + dxs[n] + px; rx = rx < 0 ? -rx : rx; rx = rx >= WW ? 126 - rx : rx;
      acc += w[n] * vp[(size_t)(ry * WW + rx) * 256];
    }
    int oy = yq + py; oy = oy >= HH ? 126 - oy : oy;
    int ox = xq + px; ox = ox >= WW ? 126 - ox : ox;
    atomicAdd(op + (size_t)(oy * WW + ox) * 256, acc);
  }
}

// K5: final projection + divide + bias. grid (192 pixtiles, 4 dtiles), block 256
__global__ void k_proj(const float* __restrict__ vacc, const float* __restrict__ zv,
                       const float* __restrict__ pw, const float* __restrict__ pb,
                       float* __restrict__ out) {
  int p0 = blockIdx.x * 64;  // global pixel (t*4096 + y*64 + x)
  int d0 = blockIdx.y * 64;
  __shared__ float sW[16][65], sV[16][65];
  int tid = threadIdx.x, ty = tid >> 4, tx = tid & 15;
  float acc[4][4] = {};
  for (int k0 = 0; k0 < 256; k0 += 16) {
    {
      int i = tid >> 4, j = tid & 15;
#pragma unroll
      for (int r = 0; r < 4; r++) sW[j][i + 16*r] = pw[(size_t)(d0 + i + 16*r) * 256 + k0 + j];
    }
    {
      int i = tid >> 4, j = tid & 15;
#pragma unroll
      for (int r = 0; r < 4; r++) sV[j][i + 16*r] = vacc[(size_t)(p0 + i + 16*r) * 256 + k0 + j];
    }
    __syncthreads();
#pragma unroll
    for (int kk = 0; kk < 16; kk++) {
      float a[4], b[4];
#pragma unroll
      for (int i = 0; i < 4; i++) a[i] = sW[kk][ty*4+i];
#pragma unroll
      for (int j = 0; j < 4; j++) b[j] = sV[kk][tx*4+j];
#pragma unroll
      for (int i = 0; i < 4; i++)
#pragma unroll
        for (int j = 0; j < 4; j++) acc[i][j] += a[i] * b[j];
    }
    __syncthreads();
  }
#pragma unroll
  for (int i = 0; i < 4; i++) {
    int d = d0 + ty*4 + i;
    float bb = pb[d];
#pragma unroll
    for (int j = 0; j < 4; j++) {
      int p = p0 + tx*4 + j;
      int t = p >> 12, pl = p & 4095;
      out[((size_t)t * 256 + d) * NPIX + pl] = acc[i][j] / zv[p] + bb;
    }
  }
}

extern "C" void kernel_launch(void* const* d_in, const int* in_sizes, int n_in,
                              void* d_out, int out_size, void* d_ws, size_t ws_size,
                              hipStream_t stream) {
  const float* vid = (const float*)d_in[0];
  const float* qdw = (const float*)d_in[1];
  const float* qpw = (const float*)d_in[2];
  const float* qb  = (const float*)d_in[3];
  const float* kdw = (const float*)d_in[4];
  const float* kpw = (const float*)d_in[5];
  const float* kb  = (const float*)d_in[6];
  const float* vdw = (const float*)d_in[7];
  const float* vpw = (const float*)d_in[8];
  const float* vb  = (const float*)d_in[9];
  const float* pw  = (const float*)d_in[10];
  const float* pb  = (const float*)d_in[11];
  float* out = (float*)d_out;
  float* ws = (float*)d_ws;

  float* dwb  = ws + OFF_DW;
  float* qbuf = ws + OFF_Q;
  float* kbuf = ws + OFF_K;
  float* vbuf = ws + OFF_V;
  float* Dbuf = ws + OFF_D;
  float* DG   = ws + OFF_DG;
  float* attn = ws + OFF_ATTN;
  int*   inds = (int*)(ws + OFF_INDS);
  float* vacc = ws + OFF_VACC;
  float* zv   = ws + OFF_ZV;

  // zero accumulators (vacc and zv are adjacent)
  hipMemsetAsync(vacc, 0, (size_t)(3145728 + 12288) * sizeof(float), stream);

  k_dw<<<dim3(768), dim3(64, 4), 0, stream>>>(vid, qdw, kdw, vdw, dwb);
  k_pw<<<dim3(64, 4, 9), 256, 0, stream>>>(dwb, qpw, qb, kpw, kb, vpw, vb,
                                           qbuf, kbuf, vbuf);
  k_dist<<<dim3(768), 256, 0, stream>>>(qbuf, kbuf, Dbuf);
  k_box<<<dim3(12, 81), 256, 0, stream>>>(Dbuf, DG);
  k_topk<<<dim3(48), 256, 0, stream>>>(DG, attn, inds);
  k_zv<<<dim3(12), 256, 0, stream>>>(zv);
  k_agg<<<dim3(3072, 4), 256, 0, stream>>>(vbuf, attn, inds, vacc);
  k_proj<<<dim3(192, 4), 256, 0, stream>>>(vacc, zv, pw, pb, out);
}